// Round 15
// baseline (3966.665 us; speedup 1.0000x reference)
//
#include <hip/hip_runtime.h>
#include <hip/hip_fp16.h>
#include <math.h>

#define NP 65536
#define MP 512
#define SKI 20
#define NBALL 10

#define FNB 16      // fps blocks
#define FPT 256     // fps threads per block (4 waves)
#define SKB2 128    // sinkhorn blocks (R9-proven optimum)
#define PKC 32      // pfeat K-chunks

// f32(-1/0.05f) rounds exactly to -20.0f
#define NINV_TAU (-20.0f)
// 1/f32(sqrt(128)) ; sc = 1/sqrt(C)
#define SCF (1.0f / 11.313708305358886719f)
#define SCNT (SCF * NINV_TAU)

typedef unsigned short us8 __attribute__((ext_vector_type(8)));
typedef _Float16 h8 __attribute__((ext_vector_type(8)));
typedef float f4 __attribute__((ext_vector_type(4)));

// ---------------- helpers ----------------

__device__ __forceinline__ float h2f(unsigned short u) {
  return __half2float(__builtin_bit_cast(__half, u));
}
__device__ __forceinline__ unsigned short f2h(float f) {
  return __builtin_bit_cast(unsigned short, __float2half(f));
}

__device__ __forceinline__ float rd_f32(const float* p) {
  return __uint_as_float(__hip_atomic_load((const unsigned int*)p,
                                           __ATOMIC_RELAXED,
                                           __HIP_MEMORY_SCOPE_AGENT));
}

// fence-free barrier: release epoch store + acquire poll (R7/R9-proven).
__device__ __forceinline__ void gbar(int* slots, int ep, int b, int t) {
  __syncthreads();
  if (t == 0) {
    __hip_atomic_store(&slots[b], ep, __ATOMIC_RELEASE, __HIP_MEMORY_SCOPE_AGENT);
  }
  if (t < SKB2) {
    while (__hip_atomic_load(&slots[t], __ATOMIC_ACQUIRE,
                             __HIP_MEMORY_SCOPE_AGENT) < ep) {}
  }
  __syncthreads();
}

// closed-form symmetric 3x3 eigenvalues (ascending), double precision
__device__ void eig3(double a00, double a01, double a02, double a11, double a12,
                     double a22, double* e) {
  double p1 = a01*a01 + a02*a02 + a12*a12;
  double q  = (a00 + a11 + a22) / 3.0;
  double b00 = a00 - q, b11 = a11 - q, b22 = a22 - q;
  double p2 = b00*b00 + b11*b11 + b22*b22 + 2.0*p1;
  if (p2 <= 1e-300) { e[0] = e[1] = e[2] = q; return; }
  double p = sqrt(p2 / 6.0);
  double ip = 1.0 / p;
  double c00 = b00*ip, c01 = a01*ip, c02 = a02*ip;
  double c11 = b11*ip, c12 = a12*ip, c22 = b22*ip;
  double detB = c00*(c11*c22 - c12*c12) - c01*(c01*c22 - c12*c02)
              + c02*(c01*c12 - c11*c02);
  double r = detB / 2.0;
  r = fmin(1.0, fmax(-1.0, r));
  double phi = acos(r) / 3.0;
  double e2 = q + 2.0*p*cos(phi);
  double e0 = q + 2.0*p*cos(phi + 2.0943951023931953);
  double e1 = 3.0*q - e2 - e0;
  e[0] = e0; e[1] = e1; e[2] = e2;
}

// ---------------- kernels ----------------

// pack xyz + |x|^2 into float4; block 0 also inits barrier/slot state
__global__ void k_prep(const float* __restrict__ xyz, float4* __restrict__ xyzs4,
                       unsigned long long* __restrict__ fslots,
                       int* __restrict__ bar1, int* __restrict__ bar2) {
  int i = blockIdx.x * blockDim.x + threadIdx.x;
  if (i < NP) {
    float x = xyz[3*i+0], y = xyz[3*i+1], z = xyz[3*i+2];
    xyzs4[i] = make_float4(x, y, z, x*x + y*y + z*z);
  }
  if (blockIdx.x == 0) {
    int t = threadIdx.x;
    if (t < 3 * FNB) fslots[t] = 0ULL;
    if (t < SKB2) { bar1[t] = 0; bar2[t] = 0; }
  }
}

// FPS: 16 blocks x 256 threads, 16 pts/thread in regs (R12/R14-proven floor).
__global__ __launch_bounds__(FPT) void k_fps3(const float4* __restrict__ xyzs4,
                                              int* __restrict__ cent,
                                              unsigned long long* __restrict__ slots) {
  const int t = threadIdx.x, b = blockIdx.x;
  const int base = (b * FPT + t) * 16;
  float X[16], Y[16], Z[16], D[16];
#pragma unroll
  for (int k = 0; k < 16; ++k) {
    float4 p = xyzs4[base + k];
    X[k] = p.x; Y[k] = p.y; Z[k] = p.z; D[k] = 1e10f;
  }
  __shared__ unsigned long long swave[4];
  __shared__ unsigned long long swin;
  int cur = 0;
  float cx = xyzs4[0].x, cy = xyzs4[0].y, cz = xyzs4[0].z;
  const int lane = t & 63, wid = t >> 6;
  for (int it = 0; it < MP; ++it) {
    if (b == 0 && t == 0) cent[it] = cur;
    float bm = -1.0f; int bi = 0x7fffffff;
#pragma unroll
    for (int k = 0; k < 16; ++k) {
      float dx = X[k] - cx, dy = Y[k] - cy, dz = Z[k] - cz;
      float d = dx*dx + dy*dy + dz*dz;
      float nd = fminf(D[k], d);
      D[k] = nd;
      bool gt = (nd > bm);
      bi = gt ? (base + k) : bi;
      bm = gt ? nd : bm;
    }
    unsigned long long key =
        ((unsigned long long)__float_as_uint(bm) << 32) |
        (unsigned int)(0x7fffffff - bi);
#pragma unroll
    for (int off = 32; off > 0; off >>= 1) {
      unsigned long long o = __shfl_down(key, off);
      key = (o > key) ? o : key;
    }
    if (lane == 0) swave[wid] = key;
    __syncthreads();
    const int p = it % 3, pn = (it + 1) % 3;
    if (t == 0) {
      unsigned long long k0 = swave[0];
      for (int w = 1; w < 4; ++w) k0 = (swave[w] > k0) ? swave[w] : k0;
      __hip_atomic_store(&slots[pn * FNB + b], 0ULL, __ATOMIC_RELAXED,
                         __HIP_MEMORY_SCOPE_AGENT);
      __hip_atomic_store(&slots[p * FNB + b], k0, __ATOMIC_RELEASE,
                         __HIP_MEMORY_SCOPE_AGENT);
    }
    if (wid == 0) {
      unsigned long long v = 0ULL;
      if (lane < FNB) {
        do {
          v = __hip_atomic_load(&slots[p * FNB + lane], __ATOMIC_ACQUIRE,
                                __HIP_MEMORY_SCOPE_AGENT);
        } while (v == 0ULL);
      }
#pragma unroll
      for (int off = 32; off > 0; off >>= 1) {
        unsigned long long o = __shfl_down(v, off);
        v = (o > v) ? o : v;
      }
      if (lane == 0) swin = v;
    }
    __syncthreads();
    unsigned long long wkey = swin;
    cur = 0x7fffffff - (int)(wkey & 0xffffffffu);
    float4 cc = xyzs4[cur];
    cx = cc.x; cy = cc.y; cz = cc.z;
  }
}

// gather proto xyz (+norm) and mean node
__global__ void k_gather1(const float* __restrict__ xyz, const int* __restrict__ cent,
                          float4* __restrict__ pxyzs4, float* __restrict__ meann) {
  __shared__ float sx[512], sy[512], sz[512];
  int m = threadIdx.x;
  int c = cent[m];
  float x = xyz[3*c+0], y = xyz[3*c+1], z = xyz[3*c+2];
  pxyzs4[m] = make_float4(x, y, z, x*x + y*y + z*z);
  sx[m] = x; sy[m] = y; sz[m] = z;
  __syncthreads();
  for (int off = 256; off > 0; off >>= 1) {
    if (m < off) { sx[m] += sx[m+off]; sy[m] += sy[m+off]; sz[m] += sz[m+off]; }
    __syncthreads();
  }
  if (m == 0) {
    meann[0] = sx[0] * (1.0f/512.0f);
    meann[1] = sy[0] * (1.0f/512.0f);
    meann[2] = sz[0] * (1.0f/512.0f);
  }
}

// gather proto features
__global__ void k_gatherf(const float* __restrict__ feats, const int* __restrict__ cent,
                          float* __restrict__ pf) {
  int m = blockIdx.x, c = threadIdx.x;
  pf[m*128 + c] = feats[(size_t)cent[m]*128 + c];
}

// ball query (first 10 smallest indices within radius) + PCA curvature -> dist_ge
__global__ void k_ballpca(const float4* __restrict__ xyzs4,
                          const float4* __restrict__ pxyzs4,
                          const float* __restrict__ meann,
                          float* __restrict__ ge) {
  const int m = blockIdx.x, t = threadIdx.x;
  __shared__ int lidx[256][NBALL];
  __shared__ int s_sel[NBALL];
  __shared__ int s_win;
  __shared__ int s_w4[4];
  float4 q = pxyzs4[m];
  int cnt = 0;
  for (int k = 0; k < 256; ++k) {
    int i = (k << 8) + t;
    float4 p = xyzs4[i];
    float dot = q.x*p.x + q.y*p.y + q.z*p.z;
    float d2 = (q.w + p.w) - 2.0f*dot;
    float d = sqrtf(fmaxf(d2, 0.0f));
    if (!(d > 0.04f) && cnt < NBALL) { lidx[t][cnt] = i; cnt++; }
  }
  __syncthreads();
  int hp = 0;
  for (int r = 0; r < NBALL; ++r) {
    int v = (hp < cnt) ? lidx[t][hp] : 0x7fffffff;
#pragma unroll
    for (int off = 32; off > 0; off >>= 1) v = min(v, __shfl_down(v, off));
    if ((t & 63) == 0) s_w4[t >> 6] = v;
    __syncthreads();
    if (t == 0) s_win = min(min(s_w4[0], s_w4[1]), min(s_w4[2], s_w4[3]));
    __syncthreads();
    int w = s_win;
    if (w != 0x7fffffff && hp < cnt && lidx[t][hp] == w) hp++;
    if (t == 0) s_sel[r] = w;
    __syncthreads();
  }
  if (t == 0) {
    float mx = meann[0], my = meann[1], mz = meann[2];
    int first = (s_sel[0] != 0x7fffffff) ? s_sel[0] : NP;
    float c00=0,c01=0,c02=0,c11=0,c12=0,c22=0;
    for (int r = 0; r < NBALL; ++r) {
      int id = s_sel[r];
      if (id == 0x7fffffff) id = first;
      float nx, ny, nz;
      if (id >= NP) { nx = mx; ny = my; nz = mz; }
      else { float4 p = xyzs4[id]; nx = p.x; ny = p.y; nz = p.z; }
      float dx = nx - q.x, dy = ny - q.y, dz = nz - q.z;
      c00 += dx*dx; c01 += dx*dy; c02 += dx*dz;
      c11 += dy*dy; c12 += dy*dz; c22 += dz*dz;
    }
    double e[3];
    eig3((double)(c00/10.0f + 1e-8f), (double)(c01/10.0f + 1e-8f),
         (double)(c02/10.0f + 1e-8f), (double)(c11/10.0f + 1e-8f),
         (double)(c12/10.0f + 1e-8f), (double)(c22/10.0f + 1e-8f), e);
    float l0 = (float)e[0], l1 = (float)e[1], l2r = (float)e[2];
    float l2 = fmaxf(l2r, 1e-8f);
    float f0 = (l2 - l1) / l2, f1 = (l1 - l0) / l2, f2 = l0 / l2;
    ge[m] = sqrtf(f0*f0 + f1*f1 + f2*f2) / sqrtf(3.0f);
  }
}

// E1t[proto][point] = fp16(exp(dist * SCNT)): block j = proto j, coalesced
// reads of xyzs4 and coalesced u16 row writes.
__global__ void k_e1t(const float4* __restrict__ xyzs4,
                      const float4* __restrict__ pxyzs4,
                      unsigned short* __restrict__ E1t) {
  const int t = threadIdx.x, j = blockIdx.x;
  const float4 q = pxyzs4[j];
  unsigned short* dst = E1t + (size_t)j * NP;
  for (int c = 0; c < 256; ++c) {
    int i = c * 256 + t;
    float4 p = xyzs4[i];
    float dot = q.x*p.x + q.y*p.y + q.z*p.z;
    float dist = sqrtf(fmaxf((q.w + p.w) - 2.0f*dot, 0.0f));
    dst[i] = f2h(__expf(dist * SCNT));
  }
}

// feats -> fp16 TRANSPOSED copy featsTh[feat][point], LDS-tiled. 1024 blocks.
__global__ void k_featht(const float* __restrict__ f, _Float16* __restrict__ ft) {
  __shared__ _Float16 sT[128][68];
  const int t = threadIdx.x;
  const int p0 = blockIdx.x * 64;
  for (int j = 0; j < 32; ++j) {
    int idx = j * 256 + t;
    int i = idx >> 7, c = idx & 127;
    sT[c][i] = (_Float16)f[(size_t)(p0 + i) * 128 + c];
  }
  __syncthreads();
  for (int j = 0; j < 32; ++j) {
    int idx = j * 256 + t;
    int c = idx >> 6, i2 = idx & 63;
    ft[(size_t)c * NP + p0 + i2] = sT[c][i2];
  }
}

// fused factorized sinkhorn 1 over E1t: 128 blocks x 512 thr, 1 barrier/iter.
// Row pass: strided-coalesced (per j, consecutive threads contiguous).
// Col pass: per-thread contiguous us8 (proto row of E1t).
__global__ __launch_bounds__(512) void k_sk1(const unsigned short* __restrict__ E1t,
                                             const float* __restrict__ ge,
                                             float* __restrict__ rr_out,
                                             float* __restrict__ gc_out,
                                             float* __restrict__ colsum,
                                             int* __restrict__ slots) {
  const int t = threadIdx.x, b = blockIdx.x;
  __shared__ float sG[MP];
  __shared__ float sGC[MP];
  __shared__ float sRr[512];
  {
    float g = __expf(ge[t] * NINV_TAU);
    sG[t] = g;
    sGC[t] = g;   // C^0 = 1
  }
  __syncthreads();
  const int row = b * 512 + t;
  const us8* c8 = (const us8*)(E1t + (size_t)t * NP + b * 512);
  for (int it = 0; it < SKI; ++it) {
    // ---- row: V = 1 + sum_j E1t[j][row] * (G_j C_j) ----
    float V = 1.0f;
    for (int j0 = 0; j0 < MP; j0 += 8) {
      float v[8];
#pragma unroll
      for (int u = 0; u < 8; ++u)
        v[u] = h2f(E1t[(size_t)(j0 + u) * NP + row]);
#pragma unroll
      for (int u = 0; u < 8; ++u)
        V = fmaf(v[u], sGC[j0 + u], V);
    }
    float Rr = 1.0f / V;
    sRr[t] = Rr;
    __syncthreads();
    // ---- col: S_t = sum over slab points of E1t[t][b*512+k] * Rr_k ----
    float S = 0.0f;
    for (int g = 0; g < 64; g += 8) {
      us8 u[8];
#pragma unroll
      for (int x = 0; x < 8; ++x) u[x] = c8[g + x];
#pragma unroll
      for (int x = 0; x < 8; ++x)
#pragma unroll
        for (int e = 0; e < 8; ++e)
          S = fmaf(h2f(u[x][e]), sRr[(g+x)*8 + e], S);
    }
    __hip_atomic_fetch_add(&colsum[it * MP + t], S, __ATOMIC_RELAXED,
                           __HIP_MEMORY_SCOPE_AGENT);
    gbar(slots, it + 1, b, t);
    // ---- new C from summed column ----
    {
      float Sm = rd_f32(&colsum[it * MP + t]);
      float Cj = 1.0f / fmaf(sG[t], Sm, 1.0f);
      sGC[t] = sG[t] * Cj;
    }
    __syncthreads();
  }
  rr_out[row] = sRr[t];
  if (b == 0) gc_out[t] = sGC[t];
}

// MFMA gamma^T @ feats: partial[kc][m][c] = gc[m]*sum_k (E1t[m][k]*rr[k])*featsTh[c][k]
// 32 blocks (K-chunks of 2048) x 256 thr (4 waves x 8 proto-tiles).
__global__ __launch_bounds__(256) void k_pfeatM(const unsigned short* __restrict__ E1t,
                                                const _Float16* __restrict__ featsTh,
                                                const float* __restrict__ gc,
                                                const float* __restrict__ rr,
                                                float* __restrict__ part) {
  __shared__ float srr[2048];
  const int t = threadIdx.x, kc = blockIdx.x;
  const int kbase = kc * 2048;
  for (int q = t; q < 2048; q += 256) srr[q] = rr[kbase + q];
  __syncthreads();
  const int w = t >> 6, l = t & 63;
  const int lr = l & 15, lk = l >> 4;
  for (int mi = 0; mi < 8; ++mi) {
    const int m0 = (w * 8 + mi) * 16;
    const us8* ea = (const us8*)(E1t + (size_t)(m0 + lr) * NP + kbase);
    f4 acc[8];
#pragma unroll
    for (int ft = 0; ft < 8; ++ft) acc[ft] = (f4){0.0f, 0.0f, 0.0f, 0.0f};
    for (int ks = 0; ks < 64; ++ks) {
      us8 ue = ea[ks * 4 + lk];
      h8 afr;
#pragma unroll
      for (int e = 0; e < 8; ++e)
        afr[e] = (_Float16)(h2f(ue[e]) * srr[ks * 32 + lk * 8 + e]);
#pragma unroll
      for (int ft = 0; ft < 8; ++ft) {
        h8 bfr = *(const h8*)(featsTh + (size_t)(ft * 16 + lr) * NP + kbase +
                              ks * 32 + lk * 8);
        acc[ft] = __builtin_amdgcn_mfma_f32_16x16x32_f16(afr, bfr, acc[ft], 0, 0, 0);
      }
    }
    float gcl[4];
#pragma unroll
    for (int r = 0; r < 4; ++r) gcl[r] = gc[m0 + lk * 4 + r];
#pragma unroll
    for (int ft = 0; ft < 8; ++ft) {
#pragma unroll
      for (int r = 0; r < 4; ++r) {
        int row = m0 + lk * 4 + r;
        int col = ft * 16 + lr;
        part[(size_t)kc * (MP * 128) + row * 128 + col] = acc[ft][r] * gcl[r];
      }
    }
  }
}

__global__ void k_pfeat_red(const float* __restrict__ part, const float* __restrict__ pf,
                            float* __restrict__ p1) {
  int idx = blockIdx.x*256 + threadIdx.x;
  float s = 0.0f;
  for (int ncb = 0; ncb < PKC; ++ncb) s += part[(size_t)ncb*MP*128 + idx];
  p1[idx] = 0.5f*pf[idx] + 0.5f*s;
}

// feats -> fp16 copy (for MFMA simpt); 4096 blocks x 256 thr, 8 elems/thread
__global__ void k_feath(const float* __restrict__ f, _Float16* __restrict__ fh) {
  int idx8 = blockIdx.x * 256 + threadIdx.x;
  float4 v0 = ((const float4*)f)[idx8 * 2];
  float4 v1 = ((const float4*)f)[idx8 * 2 + 1];
  h8 o;
  o[0] = (_Float16)v0.x; o[1] = (_Float16)v0.y;
  o[2] = (_Float16)v0.z; o[3] = (_Float16)v0.w;
  o[4] = (_Float16)v1.x; o[5] = (_Float16)v1.y;
  o[6] = (_Float16)v1.z; o[7] = (_Float16)v1.w;
  ((h8*)fh)[idx8] = o;
}

// sim column + top-20 aggregation -> p2 (f32) + p2h (fp16) + p2th (fp16 transposed)
__global__ void k_simtopk(const float* __restrict__ p1, float* __restrict__ p2,
                          _Float16* __restrict__ p2h, _Float16* __restrict__ p2th) {
  const int m = blockIdx.x, t = threadIdx.x;
  __shared__ float spm[128];
  __shared__ float scol[MP];
  __shared__ float sval[20];
  __shared__ int   sid[20];
  __shared__ float sredv[2];
  __shared__ int   sredi[2];
  __shared__ float sden;
  spm[t] = p1[m*128 + t];
  __syncthreads();
  for (int kk = t; kk < MP; kk += 128) {
    float a = 0.0f;
    const float* row = &p1[kk*128];
#pragma unroll 8
    for (int c2 = 0; c2 < 128; ++c2) a = fmaf(row[c2], spm[c2], a);
    scol[kk] = a * SCF;
  }
  __syncthreads();
  for (int rs = 0; rs < 20; ++rs) {
    float bv = -1e30f; int bI = 1 << 30;
    for (int kk = t; kk < MP; kk += 128) {
      float v = scol[kk];
      if (v > bv) { bv = v; bI = kk; }
    }
#pragma unroll
    for (int off = 32; off > 0; off >>= 1) {
      float ov = __shfl_down(bv, off); int oi = __shfl_down(bI, off);
      if (ov > bv || (ov == bv && oi < bI)) { bv = ov; bI = oi; }
    }
    if ((t & 63) == 0) { sredv[t>>6] = bv; sredi[t>>6] = bI; }
    __syncthreads();
    if (t == 0) {
      float v1 = sredv[1]; int i1 = sredi[1];
      if (v1 > bv || (v1 == bv && i1 < bI)) { bv = v1; bI = i1; }
      sval[rs] = bv; sid[rs] = bI;
      scol[bI] = -1e30f;
    }
    __syncthreads();
  }
  if (t == 0) {
    float s = 0.0f;
    for (int rs = 0; rs < 20; ++rs) s += sval[rs];
    sden = fmaxf(s, 1e-4f);
  }
  __syncthreads();
  float a = 0.0f;
  float den = sden;
  for (int rs = 0; rs < 20; ++rs) {
    float w = sval[rs] / den;
    a = fmaf(w, p1[sid[rs]*128 + t], a);
  }
  float outv = 0.5f*p1[m*128 + t] + 0.5f*a;
  p2[m*128 + t] = outv;
  p2h[m*128 + t] = (_Float16)outv;
  p2th[(size_t)t * MP + m] = (_Float16)outv;
}

// fused MFMA simpt + E2 transform (R12-proven).
__global__ __launch_bounds__(256) void k_simpt2(const _Float16* __restrict__ fh,
                                                const _Float16* __restrict__ p2h,
                                                unsigned short* __restrict__ E2,
                                                float* __restrict__ ebn) {
  __shared__ _Float16 sSim[64][516];
  __shared__ float sB[64];
  const int t = threadIdx.x;
  const int w = t >> 6, l = t & 63;
  const int m0loc = w * 16;
  const int m0 = blockIdx.x * 64 + m0loc;
  const int lr = l & 15, lk = l >> 4;
  h8 a[4];
  const _Float16* arow = fh + (size_t)(m0 + lr) * 128 + lk * 8;
#pragma unroll
  for (int kk = 0; kk < 4; ++kk) a[kk] = *(const h8*)(arow + kk * 32);
  const _Float16* brow = p2h + (size_t)lr * 128 + lk * 8;
  float minv[4] = {1e30f, 1e30f, 1e30f, 1e30f};
  for (int nt = 0; nt < 32; ++nt) {
    f4 acc = {0.0f, 0.0f, 0.0f, 0.0f};
    const _Float16* bb = brow + (size_t)nt * 16 * 128;
#pragma unroll
    for (int kk = 0; kk < 4; ++kk) {
      h8 bfr = *(const h8*)(bb + kk * 32);
      acc = __builtin_amdgcn_mfma_f32_16x16x32_f16(a[kk], bfr, acc, 0, 0, 0);
    }
#pragma unroll
    for (int r = 0; r < 4; ++r) {
      _Float16 hv = (_Float16)(acc[r] * SCF);
      sSim[m0loc + lk * 4 + r][nt * 16 + lr] = hv;
      minv[r] = fminf(minv[r], (float)hv);
    }
  }
#pragma unroll
  for (int off = 1; off < 16; off <<= 1) {
#pragma unroll
    for (int r = 0; r < 4; ++r) minv[r] = fminf(minv[r], __shfl_xor(minv[r], off));
  }
  if (lr == 0) {
#pragma unroll
    for (int r = 0; r < 4; ++r)
      sB[m0loc + lk * 4 + r] = NINV_TAU * minv[r];
  }
  __syncthreads();
  if (t < 64) ebn[blockIdx.x * 64 + t] = __expf(-sB[t]);
  for (int g = t; g < 4096; g += 256) {
    int row = g >> 6;
    int c0 = (g & 63) * 8;
    float B = sB[row];
    us8 wv;
#pragma unroll
    for (int e = 0; e < 8; ++e) {
      float v = (float)sSim[row][c0 + e];
      wv[e] = f2h(__expf(fmaf(v, NINV_TAU, -B)));
    }
    *(us8*)(E2 + (size_t)(blockIdx.x * 64 + row) * MP + c0) = wv;
  }
}

// fused factorized sinkhorn 2 over E2: 128 blocks x 512 thr, 1 barrier/iter (R9).
__global__ __launch_bounds__(512) void k_sk2(const unsigned short* __restrict__ E2,
                                             const float* __restrict__ ebn,
                                             float* __restrict__ rr_out,
                                             float* __restrict__ c_out,
                                             float* __restrict__ colsum,
                                             int* __restrict__ slots) {
  const int t = threadIdx.x, b = blockIdx.x;
  __shared__ float sC[MP];
  __shared__ float sRr[512];
  sC[t] = 1.0f;
  __syncthreads();
  const int row = b * 512 + t;
  const us8* e8 = (const us8*)(E2 + (size_t)row * MP);
  const float eb = ebn[row];
  for (int it = 0; it < SKI; ++it) {
    float V = eb;
    for (int g0 = 0; g0 < 64; g0 += 8) {
      us8 u[8];
#pragma unroll
      for (int g = 0; g < 8; ++g) u[g] = e8[g0 + g];
#pragma unroll
      for (int g = 0; g < 8; ++g)
#pragma unroll
        for (int e = 0; e < 8; ++e)
          V = fmaf(h2f(u[g][e]), sC[(g0+g)*8 + e], V);
    }
    float R = 1.0f / V;
    sRr[t] = R;
    __syncthreads();
    float S = 0.0f;
    for (int k0 = 0; k0 < 512; k0 += 8) {
      float v[8];
#pragma unroll
      for (int u2 = 0; u2 < 8; ++u2)
        v[u2] = h2f(E2[(size_t)(b*512 + k0 + u2) * MP + t]);
#pragma unroll
      for (int u2 = 0; u2 < 8; ++u2)
        S = fmaf(v[u2], sRr[k0 + u2], S);
    }
    __hip_atomic_fetch_add(&colsum[it * MP + t], S, __ATOMIC_RELAXED,
                           __HIP_MEMORY_SCOPE_AGENT);
    gbar(slots, it + 1, b, t);
    {
      float Sm = rd_f32(&colsum[it * MP + t]);
      sC[t] = 1.0f / (Sm + 1.0f);
    }
    __syncthreads();
  }
  rr_out[row] = sRr[t];
  if (b == 0) c_out[t] = sC[t];
}

// refined = 0.5*feats + 0.5 * W @ p2, W = E2 * R_i * C_j -- fp16 MFMA (R14-proven).
__global__ __launch_bounds__(256) void k_refined2(const unsigned short* __restrict__ E2,
                                                  const float* __restrict__ rr,
                                                  const float* __restrict__ cc,
                                                  const _Float16* __restrict__ p2th,
                                                  const float* __restrict__ feats,
                                                  float* __restrict__ out) {
  __shared__ float scc[MP];
  const int t = threadIdx.x;
  scc[t] = cc[t];
  scc[t + 256] = cc[t + 256];
  __syncthreads();
  const int w = t >> 6, l = t & 63;
  const int m0 = blockIdx.x * 64 + w * 16;
  const int lr = l & 15, lk = l >> 4;
  const int rowA = m0 + lr;
  const float Rf = rr[rowA];
  h8 af[16];
  const us8* e8 = (const us8*)(E2 + (size_t)rowA * MP);
#pragma unroll
  for (int s = 0; s < 16; ++s) {
    us8 uv = e8[s * 4 + lk];
#pragma unroll
    for (int e = 0; e < 8; ++e) {
      float wv = h2f(uv[e]) * Rf * scc[s * 32 + lk * 8 + e];
      af[s][e] = (_Float16)wv;
    }
  }
  for (int ft = 0; ft < 8; ++ft) {
    f4 acc = {0.0f, 0.0f, 0.0f, 0.0f};
    const _Float16* bbase = p2th + (size_t)(ft * 16 + lr) * MP + lk * 8;
#pragma unroll
    for (int s = 0; s < 16; ++s) {
      h8 bf = *(const h8*)(bbase + s * 32);
      acc = __builtin_amdgcn_mfma_f32_16x16x32_f16(af[s], bf, acc, 0, 0, 0);
    }
#pragma unroll
    for (int r = 0; r < 4; ++r) {
      int row = m0 + lk * 4 + r;
      int col = ft * 16 + lr;
      out[(size_t)row * 128 + col] =
          0.5f * feats[(size_t)row * 128 + col] + 0.5f * acc[r];
    }
  }
}

// ---------------- launcher ----------------

extern "C" void kernel_launch(void* const* d_in, const int* in_sizes, int n_in,
                              void* d_out, int out_size, void* d_ws, size_t ws_size,
                              hipStream_t stream) {
  (void)in_sizes; (void)n_in; (void)out_size; (void)ws_size;
  const float* xyz   = (const float*)d_in[0];
  const float* feats = (const float*)d_in[1];
  float* out = (float*)d_out;
  char* ws = (char*)d_ws;

  auto al = [](size_t x) { return (x + 255) & ~(size_t)255; };
  // E-buffer (fp16, 64MB): E1t [proto][point], later overwritten by E2 [point][proto]
  unsigned short* Ebuf = (unsigned short*)ws;
  size_t o = al((size_t)NP * MP * 2);
  float4* xyzs4 = (float4*)(ws + o); o += al((size_t)NP * 16);
  float* rbuf   = (float*)(ws + o);  o += al((size_t)NP * 4);
  float* ebnbuf = (float*)(ws + o);  o += al((size_t)NP * 4);
  float* cbuf   = (float*)(ws + o);  o += al((size_t)MP * 4);
  float* gcbuf  = (float*)(ws + o);  o += al((size_t)MP * 4);
  int*   cent   = (int*)(ws + o);    o += al((size_t)MP * 4);
  float4* pxyzs4 = (float4*)(ws + o); o += al((size_t)MP * 16);
  float* ge     = (float*)(ws + o);  o += al((size_t)MP * 4);
  float* meann  = (float*)(ws + o);  o += al((size_t)256);
  float* pf     = (float*)(ws + o);  o += al((size_t)MP * 128 * 4);
  float* p1     = (float*)(ws + o);  o += al((size_t)MP * 128 * 4);
  float* p2     = (float*)(ws + o);  o += al((size_t)MP * 128 * 4);
  _Float16* p2h = (_Float16*)(ws + o); o += al((size_t)MP * 128 * 2);
  _Float16* p2th = (_Float16*)(ws + o); o += al((size_t)MP * 128 * 2);
  float* colsumA = (float*)(ws + o); o += al((size_t)SKI * MP * 4);
  float* colsumB = (float*)(ws + o); o += al((size_t)SKI * MP * 4);
  unsigned long long* fslots = (unsigned long long*)(ws + o);
  o += al((size_t)3 * FNB * 8);
  int* bar1 = (int*)(ws + o); o += al((size_t)SKB2 * 4);
  int* bar2 = (int*)(ws + o); o += al((size_t)SKB2 * 4);
  // partA (16.8MB): featsTh (early) then featsh (late, for simpt2)
  float* partA = (float*)(ws + o); o += al((size_t)64 * MP * 128 * 4);
  _Float16* featsTh = (_Float16*)partA;
  _Float16* featsh  = (_Float16*)partA;
  // pfeat partials (PKC x 512 x 128 f32 = 8.4MB)
  float* partM = (float*)(ws + o); o += al((size_t)PKC * MP * 128 * 4);

  hipMemsetAsync(colsumA, 0, (size_t)2 * SKI * MP * 4 + 256, stream);
  k_prep<<<dim3(256), dim3(256), 0, stream>>>(xyz, xyzs4, fslots, bar1, bar2);
  k_fps3<<<dim3(FNB), dim3(FPT), 0, stream>>>(xyzs4, cent, fslots);
  k_gather1<<<dim3(1), dim3(512), 0, stream>>>(xyz, cent, pxyzs4, meann);
  k_gatherf<<<dim3(512), dim3(128), 0, stream>>>(feats, cent, pf);
  k_ballpca<<<dim3(512), dim3(256), 0, stream>>>(xyzs4, pxyzs4, meann, ge);

  // sinkhorn 1 on transposed E1t (factorized, exp-free, fence-free)
  k_e1t<<<dim3(512), dim3(256), 0, stream>>>(xyzs4, pxyzs4, Ebuf);
  k_featht<<<dim3(1024), dim3(256), 0, stream>>>(feats, featsTh);
  k_sk1<<<dim3(SKB2), dim3(512), 0, stream>>>(Ebuf, ge, rbuf, gcbuf, colsumA, bar1);

  // p1 = 0.5*pf + 0.5*gamma^T feats  via MFMA over E1t/featsTh
  k_pfeatM<<<dim3(PKC), dim3(256), 0, stream>>>(Ebuf, featsTh, gcbuf, rbuf, partM);
  k_pfeat_red<<<dim3(256), dim3(256), 0, stream>>>(partM, pf, p1);
  k_simtopk<<<dim3(512), dim3(128), 0, stream>>>(p1, p2, p2h, p2th);

  // feats -> fp16 (overwrites featsTh, now dead), fused MFMA sim + E2, sinkhorn 2
  k_feath<<<dim3(4096), dim3(256), 0, stream>>>(feats, featsh);
  k_simpt2<<<dim3(1024), dim3(256), 0, stream>>>(featsh, p2h, Ebuf, ebnbuf);
  k_sk2<<<dim3(SKB2), dim3(512), 0, stream>>>(Ebuf, ebnbuf, rbuf, cbuf, colsumB, bar2);
  k_refined2<<<dim3(1024), dim3(256), 0, stream>>>(Ebuf, rbuf, cbuf, p2th, feats, out);
}

// Round 16
// 3382.681 us; speedup vs baseline: 1.1726x; 1.1726x over previous
//
#include <hip/hip_runtime.h>
#include <hip/hip_fp16.h>
#include <math.h>

#define NP 65536
#define MP 512
#define SKI 20
#define NBALL 10

#define FNB 16      // fps blocks
#define FPT 256     // fps threads per block (4 waves)
#define SKB2 128    // sinkhorn blocks (R9-proven optimum)

// f32(-1/0.05f) rounds exactly to -20.0f
#define NINV_TAU (-20.0f)
// 1/f32(sqrt(128)) ; sc = 1/sqrt(C)
#define SCF (1.0f / 11.313708305358886719f)
#define SCNT (SCF * NINV_TAU)

typedef unsigned short us8 __attribute__((ext_vector_type(8)));
typedef _Float16 h8 __attribute__((ext_vector_type(8)));
typedef float f4 __attribute__((ext_vector_type(4)));

// ---------------- helpers ----------------

__device__ __forceinline__ float h2f(unsigned short u) {
  return __half2float(__builtin_bit_cast(__half, u));
}
__device__ __forceinline__ unsigned short f2h(float f) {
  return __builtin_bit_cast(unsigned short, __float2half(f));
}

__device__ __forceinline__ float rd_f32(const float* p) {
  return __uint_as_float(__hip_atomic_load((const unsigned int*)p,
                                           __ATOMIC_RELAXED,
                                           __HIP_MEMORY_SCOPE_AGENT));
}

// fence-free barrier: release epoch store + acquire poll (R7/R9-proven).
__device__ __forceinline__ void gbar(int* slots, int ep, int b, int t) {
  __syncthreads();
  if (t == 0) {
    __hip_atomic_store(&slots[b], ep, __ATOMIC_RELEASE, __HIP_MEMORY_SCOPE_AGENT);
  }
  if (t < SKB2) {
    while (__hip_atomic_load(&slots[t], __ATOMIC_ACQUIRE,
                             __HIP_MEMORY_SCOPE_AGENT) < ep) {}
  }
  __syncthreads();
}

// closed-form symmetric 3x3 eigenvalues (ascending), double precision
__device__ void eig3(double a00, double a01, double a02, double a11, double a12,
                     double a22, double* e) {
  double p1 = a01*a01 + a02*a02 + a12*a12;
  double q  = (a00 + a11 + a22) / 3.0;
  double b00 = a00 - q, b11 = a11 - q, b22 = a22 - q;
  double p2 = b00*b00 + b11*b11 + b22*b22 + 2.0*p1;
  if (p2 <= 1e-300) { e[0] = e[1] = e[2] = q; return; }
  double p = sqrt(p2 / 6.0);
  double ip = 1.0 / p;
  double c00 = b00*ip, c01 = a01*ip, c02 = a02*ip;
  double c11 = b11*ip, c12 = a12*ip, c22 = b22*ip;
  double detB = c00*(c11*c22 - c12*c12) - c01*(c01*c22 - c12*c02)
              + c02*(c01*c12 - c11*c02);
  double r = detB / 2.0;
  r = fmin(1.0, fmax(-1.0, r));
  double phi = acos(r) / 3.0;
  double e2 = q + 2.0*p*cos(phi);
  double e0 = q + 2.0*p*cos(phi + 2.0943951023931953);
  double e1 = 3.0*q - e2 - e0;
  e[0] = e0; e[1] = e1; e[2] = e2;
}

// ---------------- kernels ----------------

// pack xyz + |x|^2 into float4; block 0 also inits barrier/slot state
__global__ void k_prep(const float* __restrict__ xyz, float4* __restrict__ xyzs4,
                       unsigned long long* __restrict__ fslots,
                       int* __restrict__ bar1, int* __restrict__ bar2) {
  int i = blockIdx.x * blockDim.x + threadIdx.x;
  if (i < NP) {
    float x = xyz[3*i+0], y = xyz[3*i+1], z = xyz[3*i+2];
    xyzs4[i] = make_float4(x, y, z, x*x + y*y + z*z);
  }
  if (blockIdx.x == 0) {
    int t = threadIdx.x;
    if (t < 3 * FNB) fslots[t] = 0ULL;
    if (t < SKB2) { bar1[t] = 0; bar2[t] = 0; }
  }
}

// FPS: 16 blocks x 256 threads, 16 pts/thread in regs. Payload slot barrier,
// mod-3 phase buffering, streamlined 2-syncthreads iteration.
__global__ __launch_bounds__(FPT) void k_fps3(const float4* __restrict__ xyzs4,
                                              int* __restrict__ cent,
                                              unsigned long long* __restrict__ slots) {
  const int t = threadIdx.x, b = blockIdx.x;
  const int base = (b * FPT + t) * 16;
  float X[16], Y[16], Z[16], D[16];
#pragma unroll
  for (int k = 0; k < 16; ++k) {
    float4 p = xyzs4[base + k];
    X[k] = p.x; Y[k] = p.y; Z[k] = p.z; D[k] = 1e10f;
  }
  __shared__ unsigned long long swave[4];
  __shared__ unsigned long long swin;
  int cur = 0;
  float cx = xyzs4[0].x, cy = xyzs4[0].y, cz = xyzs4[0].z;
  const int lane = t & 63, wid = t >> 6;
  for (int it = 0; it < MP; ++it) {
    if (b == 0 && t == 0) cent[it] = cur;
    float bm = -1.0f; int bi = 0x7fffffff;
#pragma unroll
    for (int k = 0; k < 16; ++k) {
      float dx = X[k] - cx, dy = Y[k] - cy, dz = Z[k] - cz;
      float d = dx*dx + dy*dy + dz*dz;
      float nd = fminf(D[k], d);
      D[k] = nd;
      bool gt = (nd > bm);
      bi = gt ? (base + k) : bi;
      bm = gt ? nd : bm;
    }
    unsigned long long key =
        ((unsigned long long)__float_as_uint(bm) << 32) |
        (unsigned int)(0x7fffffff - bi);
#pragma unroll
    for (int off = 32; off > 0; off >>= 1) {
      unsigned long long o = __shfl_down(key, off);
      key = (o > key) ? o : key;
    }
    if (lane == 0) swave[wid] = key;
    __syncthreads();
    const int p = it % 3, pn = (it + 1) % 3;
    if (t == 0) {
      unsigned long long k0 = swave[0];
      for (int w = 1; w < 4; ++w) k0 = (swave[w] > k0) ? swave[w] : k0;
      __hip_atomic_store(&slots[pn * FNB + b], 0ULL, __ATOMIC_RELAXED,
                         __HIP_MEMORY_SCOPE_AGENT);
      __hip_atomic_store(&slots[p * FNB + b], k0, __ATOMIC_RELEASE,
                         __HIP_MEMORY_SCOPE_AGENT);
    }
    if (wid == 0) {
      unsigned long long v = 0ULL;
      if (lane < FNB) {
        do {
          v = __hip_atomic_load(&slots[p * FNB + lane], __ATOMIC_ACQUIRE,
                                __HIP_MEMORY_SCOPE_AGENT);
        } while (v == 0ULL);
      }
#pragma unroll
      for (int off = 32; off > 0; off >>= 1) {
        unsigned long long o = __shfl_down(v, off);
        v = (o > v) ? o : v;
      }
      if (lane == 0) swin = v;
    }
    __syncthreads();
    unsigned long long wkey = swin;
    cur = 0x7fffffff - (int)(wkey & 0xffffffffu);
    float4 cc = xyzs4[cur];
    cx = cc.x; cy = cc.y; cz = cc.z;
  }
}

// gather proto xyz (+norm) and mean node
__global__ void k_gather1(const float* __restrict__ xyz, const int* __restrict__ cent,
                          float4* __restrict__ pxyzs4, float* __restrict__ meann) {
  __shared__ float sx[512], sy[512], sz[512];
  int m = threadIdx.x;
  int c = cent[m];
  float x = xyz[3*c+0], y = xyz[3*c+1], z = xyz[3*c+2];
  pxyzs4[m] = make_float4(x, y, z, x*x + y*y + z*z);
  sx[m] = x; sy[m] = y; sz[m] = z;
  __syncthreads();
  for (int off = 256; off > 0; off >>= 1) {
    if (m < off) { sx[m] += sx[m+off]; sy[m] += sy[m+off]; sz[m] += sz[m+off]; }
    __syncthreads();
  }
  if (m == 0) {
    meann[0] = sx[0] * (1.0f/512.0f);
    meann[1] = sy[0] * (1.0f/512.0f);
    meann[2] = sz[0] * (1.0f/512.0f);
  }
}

// gather proto features
__global__ void k_gatherf(const float* __restrict__ feats, const int* __restrict__ cent,
                          float* __restrict__ pf) {
  int m = blockIdx.x, c = threadIdx.x;
  pf[m*128 + c] = feats[(size_t)cent[m]*128 + c];
}

// ball query (first 10 smallest indices within radius) + PCA curvature -> dist_ge
__global__ void k_ballpca(const float4* __restrict__ xyzs4,
                          const float4* __restrict__ pxyzs4,
                          const float* __restrict__ meann,
                          float* __restrict__ ge) {
  const int m = blockIdx.x, t = threadIdx.x;
  __shared__ int lidx[256][NBALL];
  __shared__ int s_sel[NBALL];
  __shared__ int s_win;
  __shared__ int s_w4[4];
  float4 q = pxyzs4[m];
  int cnt = 0;
  for (int k = 0; k < 256; ++k) {
    int i = (k << 8) + t;
    float4 p = xyzs4[i];
    float dot = q.x*p.x + q.y*p.y + q.z*p.z;
    float d2 = (q.w + p.w) - 2.0f*dot;
    float d = sqrtf(fmaxf(d2, 0.0f));
    if (!(d > 0.04f) && cnt < NBALL) { lidx[t][cnt] = i; cnt++; }
  }
  __syncthreads();
  int hp = 0;
  for (int r = 0; r < NBALL; ++r) {
    int v = (hp < cnt) ? lidx[t][hp] : 0x7fffffff;
#pragma unroll
    for (int off = 32; off > 0; off >>= 1) v = min(v, __shfl_down(v, off));
    if ((t & 63) == 0) s_w4[t >> 6] = v;
    __syncthreads();
    if (t == 0) s_win = min(min(s_w4[0], s_w4[1]), min(s_w4[2], s_w4[3]));
    __syncthreads();
    int w = s_win;
    if (w != 0x7fffffff && hp < cnt && lidx[t][hp] == w) hp++;
    if (t == 0) s_sel[r] = w;
    __syncthreads();
  }
  if (t == 0) {
    float mx = meann[0], my = meann[1], mz = meann[2];
    int first = (s_sel[0] != 0x7fffffff) ? s_sel[0] : NP;
    float c00=0,c01=0,c02=0,c11=0,c12=0,c22=0;
    for (int r = 0; r < NBALL; ++r) {
      int id = s_sel[r];
      if (id == 0x7fffffff) id = first;
      float nx, ny, nz;
      if (id >= NP) { nx = mx; ny = my; nz = mz; }
      else { float4 p = xyzs4[id]; nx = p.x; ny = p.y; nz = p.z; }
      float dx = nx - q.x, dy = ny - q.y, dz = nz - q.z;
      c00 += dx*dx; c01 += dx*dy; c02 += dx*dz;
      c11 += dy*dy; c12 += dy*dz; c22 += dz*dz;
    }
    double e[3];
    eig3((double)(c00/10.0f + 1e-8f), (double)(c01/10.0f + 1e-8f),
         (double)(c02/10.0f + 1e-8f), (double)(c11/10.0f + 1e-8f),
         (double)(c12/10.0f + 1e-8f), (double)(c22/10.0f + 1e-8f), e);
    float l0 = (float)e[0], l1 = (float)e[1], l2r = (float)e[2];
    float l2 = fmaxf(l2r, 1e-8f);
    float f0 = (l2 - l1) / l2, f1 = (l1 - l0) / l2, f2 = l0 / l2;
    ge[m] = sqrtf(f0*f0 + f1*f1 + f2*f2) / sqrtf(3.0f);
  }
}

// E1 = fp16(exp(dist(i,j) * SCNT)); 512 blocks x 256 thr; 2 thr/row, 256 cols each
__global__ void k_e1(const float4* __restrict__ xyzs4,
                     const float4* __restrict__ pxyzs4,
                     unsigned short* __restrict__ E1) {
  const int t = threadIdx.x, b = blockIdx.x;
  __shared__ float4 spp[MP];
  spp[t] = pxyzs4[t];
  spp[t + 256] = pxyzs4[t + 256];
  __syncthreads();
  const int row = b * 128 + (t >> 1);
  const int h = t & 1;
  const float4 q = xyzs4[row];
  us8* dst = (us8*)(E1 + (size_t)row * MP + h * 256);
  for (int g = 0; g < 32; ++g) {
    us8 v;
#pragma unroll
    for (int e = 0; e < 8; ++e) {
      float4 p = spp[h*256 + g*8 + e];
      float dot = q.x*p.x + q.y*p.y + q.z*p.z;
      float dist = sqrtf(fmaxf((q.w + p.w) - 2.0f*dot, 0.0f));
      v[e] = f2h(__expf(dist * SCNT));
    }
    dst[g] = v;
  }
}

// fused factorized sinkhorn 1: 128 blocks x 512 thr, 1 barrier/iter (R9-proven).
__global__ __launch_bounds__(512) void k_sk1(const unsigned short* __restrict__ E1,
                                             const float* __restrict__ ge,
                                             float* __restrict__ rr_out,
                                             float* __restrict__ gc_out,
                                             float* __restrict__ colsum,
                                             int* __restrict__ slots) {
  const int t = threadIdx.x, b = blockIdx.x;
  __shared__ float sG[MP];
  __shared__ float sGC[MP];
  __shared__ float sRr[512];
  {
    float g = __expf(ge[t] * NINV_TAU);
    sG[t] = g;
    sGC[t] = g;   // C^0 = 1
  }
  __syncthreads();
  const int row = b * 512 + t;
  const us8* e8 = (const us8*)(E1 + (size_t)row * MP);
  for (int it = 0; it < SKI; ++it) {
    // ---- row: V = 1 + sum_j E1_ij * (G_j C_j) ----
    float V = 1.0f;
    for (int g0 = 0; g0 < 64; g0 += 8) {
      us8 u[8];
#pragma unroll
      for (int g = 0; g < 8; ++g) u[g] = e8[g0 + g];
#pragma unroll
      for (int g = 0; g < 8; ++g)
#pragma unroll
        for (int e = 0; e < 8; ++e)
          V = fmaf(h2f(u[g][e]), sGC[(g0+g)*8 + e], V);
    }
    float Rr = 1.0f / V;
    sRr[t] = Rr;
    __syncthreads();
    // ---- col: S_t = sum over slab rows of E1_(row,t) * Rr_row ----
    float S = 0.0f;
    for (int k0 = 0; k0 < 512; k0 += 8) {
      float v[8];
#pragma unroll
      for (int u2 = 0; u2 < 8; ++u2)
        v[u2] = h2f(E1[(size_t)(b*512 + k0 + u2) * MP + t]);
#pragma unroll
      for (int u2 = 0; u2 < 8; ++u2)
        S = fmaf(v[u2], sRr[k0 + u2], S);
    }
    __hip_atomic_fetch_add(&colsum[it * MP + t], S, __ATOMIC_RELAXED,
                           __HIP_MEMORY_SCOPE_AGENT);
    gbar(slots, it + 1, b, t);
    // ---- new C from summed column ----
    {
      float Sm = rd_f32(&colsum[it * MP + t]);
      float Cj = 1.0f / fmaf(sG[t], Sm, 1.0f);
      sGC[t] = sG[t] * Cj;
    }
    __syncthreads();
  }
  rr_out[row] = sRr[t];
  if (b == 0) gc_out[t] = sGC[t];
}

// partial gamma^T @ feats using E1: gamma = E1 * gc_j * rr_i
__global__ void k_pfeat_part(const unsigned short* __restrict__ E1,
                             const float* __restrict__ gc, const float* __restrict__ rr,
                             const float* __restrict__ feats,
                             float* __restrict__ part) {
  const int t = threadIdx.x;
  const int nc = blockIdx.x;
  const int mt = blockIdx.y;
  __shared__ float sgc[64];
  __shared__ float sf[64][128];
  __shared__ float sw[64][64];
  __shared__ float srr[64];
  if (t < 64) sgc[t] = gc[mt*64 + t];
  const int mg = t >> 4;
  const int cg = t & 15;
  float acc[8][8];
#pragma unroll
  for (int a = 0; a < 8; ++a)
#pragma unroll
    for (int b2 = 0; b2 < 8; ++b2) acc[a][b2] = 0.0f;
  for (int bt = 0; bt < 16; ++bt) {
    int n0 = nc*1024 + bt*64;
    __syncthreads();
    for (int q2 = t; q2 < 2048; q2 += 128) {
      int row = q2 >> 5, c4 = q2 & 31;
      ((float4*)&sf[row][0])[c4] = ((const float4*)feats)[(size_t)(n0+row)*32 + c4];
    }
    if (t < 64) srr[t] = rr[n0 + t];
    __syncthreads();
    for (int q2 = t; q2 < 4096; q2 += 128) {
      int nl = q2 >> 6, ml = q2 & 63;
      float ev = h2f(E1[(size_t)(n0+nl)*MP + mt*64 + ml]);
      sw[nl][ml] = ev * sgc[ml] * srr[nl];
    }
    __syncthreads();
#pragma unroll 8
    for (int n = 0; n < 64; ++n) {
      float4 w0 = ((float4*)&sw[n][0])[mg*2];
      float4 w1 = ((float4*)&sw[n][0])[mg*2+1];
      float4 f0 = ((float4*)&sf[n][0])[cg*2];
      float4 f1 = ((float4*)&sf[n][0])[cg*2+1];
      float wv[8] = {w0.x,w0.y,w0.z,w0.w,w1.x,w1.y,w1.z,w1.w};
      float fv[8] = {f0.x,f0.y,f0.z,f0.w,f1.x,f1.y,f1.z,f1.w};
#pragma unroll
      for (int a = 0; a < 8; ++a)
#pragma unroll
        for (int b2 = 0; b2 < 8; ++b2) acc[a][b2] = fmaf(wv[a], fv[b2], acc[a][b2]);
    }
  }
  for (int a = 0; a < 8; ++a) {
    int m = mt*64 + mg*8 + a;
    float* dst = &part[((size_t)nc*MP + m)*128 + cg*8];
    ((float4*)dst)[0] = make_float4(acc[a][0], acc[a][1], acc[a][2], acc[a][3]);
    ((float4*)dst)[1] = make_float4(acc[a][4], acc[a][5], acc[a][6], acc[a][7]);
  }
}

__global__ void k_pfeat_red(const float* __restrict__ part, const float* __restrict__ pf,
                            float* __restrict__ p1) {
  int idx = blockIdx.x*256 + threadIdx.x;
  float s = 0.0f;
  for (int ncb = 0; ncb < 64; ++ncb) s += part[(size_t)ncb*MP*128 + idx];
  p1[idx] = 0.5f*pf[idx] + 0.5f*s;
}

// feats -> fp16 copy (for MFMA simpt); 4096 blocks x 256 thr, 8 elems/thread
__global__ void k_feath(const float* __restrict__ f, _Float16* __restrict__ fh) {
  int idx8 = blockIdx.x * 256 + threadIdx.x;
  float4 v0 = ((const float4*)f)[idx8 * 2];
  float4 v1 = ((const float4*)f)[idx8 * 2 + 1];
  h8 o;
  o[0] = (_Float16)v0.x; o[1] = (_Float16)v0.y;
  o[2] = (_Float16)v0.z; o[3] = (_Float16)v0.w;
  o[4] = (_Float16)v1.x; o[5] = (_Float16)v1.y;
  o[6] = (_Float16)v1.z; o[7] = (_Float16)v1.w;
  ((h8*)fh)[idx8] = o;
}

// sim column + top-20 aggregation -> p2 (f32) + p2h (fp16) + p2th (fp16 transposed)
__global__ void k_simtopk(const float* __restrict__ p1, float* __restrict__ p2,
                          _Float16* __restrict__ p2h, _Float16* __restrict__ p2th) {
  const int m = blockIdx.x, t = threadIdx.x;
  __shared__ float spm[128];
  __shared__ float scol[MP];
  __shared__ float sval[20];
  __shared__ int   sid[20];
  __shared__ float sredv[2];
  __shared__ int   sredi[2];
  __shared__ float sden;
  spm[t] = p1[m*128 + t];
  __syncthreads();
  for (int kk = t; kk < MP; kk += 128) {
    float a = 0.0f;
    const float* row = &p1[kk*128];
#pragma unroll 8
    for (int c2 = 0; c2 < 128; ++c2) a = fmaf(row[c2], spm[c2], a);
    scol[kk] = a * SCF;
  }
  __syncthreads();
  for (int rs = 0; rs < 20; ++rs) {
    float bv = -1e30f; int bI = 1 << 30;
    for (int kk = t; kk < MP; kk += 128) {
      float v = scol[kk];
      if (v > bv) { bv = v; bI = kk; }
    }
#pragma unroll
    for (int off = 32; off > 0; off >>= 1) {
      float ov = __shfl_down(bv, off); int oi = __shfl_down(bI, off);
      if (ov > bv || (ov == bv && oi < bI)) { bv = ov; bI = oi; }
    }
    if ((t & 63) == 0) { sredv[t>>6] = bv; sredi[t>>6] = bI; }
    __syncthreads();
    if (t == 0) {
      float v1 = sredv[1]; int i1 = sredi[1];
      if (v1 > bv || (v1 == bv && i1 < bI)) { bv = v1; bI = i1; }
      sval[rs] = bv; sid[rs] = bI;
      scol[bI] = -1e30f;
    }
    __syncthreads();
  }
  if (t == 0) {
    float s = 0.0f;
    for (int rs = 0; rs < 20; ++rs) s += sval[rs];
    sden = fmaxf(s, 1e-4f);
  }
  __syncthreads();
  float a = 0.0f;
  float den = sden;
  for (int rs = 0; rs < 20; ++rs) {
    float w = sval[rs] / den;
    a = fmaf(w, p1[sid[rs]*128 + t], a);
  }
  float outv = 0.5f*p1[m*128 + t] + 0.5f*a;
  p2[m*128 + t] = outv;
  p2h[m*128 + t] = (_Float16)outv;
  p2th[(size_t)t * MP + m] = (_Float16)outv;
}

// fused MFMA simpt + E2 transform (R12-proven).
__global__ __launch_bounds__(256) void k_simpt2(const _Float16* __restrict__ fh,
                                                const _Float16* __restrict__ p2h,
                                                unsigned short* __restrict__ E2,
                                                float* __restrict__ ebn) {
  __shared__ _Float16 sSim[64][516];   // padded: 2-way-free LDS banking
  __shared__ float sB[64];
  const int t = threadIdx.x;
  const int w = t >> 6, l = t & 63;
  const int m0loc = w * 16;
  const int m0 = blockIdx.x * 64 + m0loc;
  const int lr = l & 15, lk = l >> 4;
  h8 a[4];
  const _Float16* arow = fh + (size_t)(m0 + lr) * 128 + lk * 8;
#pragma unroll
  for (int kk = 0; kk < 4; ++kk) a[kk] = *(const h8*)(arow + kk * 32);
  const _Float16* brow = p2h + (size_t)lr * 128 + lk * 8;
  float minv[4] = {1e30f, 1e30f, 1e30f, 1e30f};
  for (int nt = 0; nt < 32; ++nt) {
    f4 acc = {0.0f, 0.0f, 0.0f, 0.0f};
    const _Float16* bb = brow + (size_t)nt * 16 * 128;
#pragma unroll
    for (int kk = 0; kk < 4; ++kk) {
      h8 bfr = *(const h8*)(bb + kk * 32);
      acc = __builtin_amdgcn_mfma_f32_16x16x32_f16(a[kk], bfr, acc, 0, 0, 0);
    }
#pragma unroll
    for (int r = 0; r < 4; ++r) {
      _Float16 hv = (_Float16)(acc[r] * SCF);
      sSim[m0loc + lk * 4 + r][nt * 16 + lr] = hv;
      minv[r] = fminf(minv[r], (float)hv);   // min of fp16-rounded value
    }
  }
#pragma unroll
  for (int off = 1; off < 16; off <<= 1) {
#pragma unroll
    for (int r = 0; r < 4; ++r) minv[r] = fminf(minv[r], __shfl_xor(minv[r], off));
  }
  if (lr == 0) {
#pragma unroll
    for (int r = 0; r < 4; ++r)
      sB[m0loc + lk * 4 + r] = NINV_TAU * minv[r];   // B = max(sim*NT) = NT*min
  }
  __syncthreads();
  if (t < 64) ebn[blockIdx.x * 64 + t] = __expf(-sB[t]);
  for (int g = t; g < 4096; g += 256) {
    int row = g >> 6;
    int c0 = (g & 63) * 8;
    float B = sB[row];
    us8 wv;
#pragma unroll
    for (int e = 0; e < 8; ++e) {
      float v = (float)sSim[row][c0 + e];
      wv[e] = f2h(__expf(fmaf(v, NINV_TAU, -B)));
    }
    *(us8*)(E2 + (size_t)(blockIdx.x * 64 + row) * MP + c0) = wv;
  }
}

// fused factorized sinkhorn 2 over E2: 128 blocks x 512 thr, 1 barrier/iter (R9).
__global__ __launch_bounds__(512) void k_sk2(const unsigned short* __restrict__ E2,
                                             const float* __restrict__ ebn,
                                             float* __restrict__ rr_out,
                                             float* __restrict__ c_out,
                                             float* __restrict__ colsum,
                                             int* __restrict__ slots) {
  const int t = threadIdx.x, b = blockIdx.x;
  __shared__ float sC[MP];
  __shared__ float sRr[512];
  sC[t] = 1.0f;
  __syncthreads();
  const int row = b * 512 + t;
  const us8* e8 = (const us8*)(E2 + (size_t)row * MP);
  const float eb = ebn[row];
  for (int it = 0; it < SKI; ++it) {
    float V = eb;
    for (int g0 = 0; g0 < 64; g0 += 8) {
      us8 u[8];
#pragma unroll
      for (int g = 0; g < 8; ++g) u[g] = e8[g0 + g];
#pragma unroll
      for (int g = 0; g < 8; ++g)
#pragma unroll
        for (int e = 0; e < 8; ++e)
          V = fmaf(h2f(u[g][e]), sC[(g0+g)*8 + e], V);
    }
    float R = 1.0f / V;
    sRr[t] = R;
    __syncthreads();
    float S = 0.0f;
    for (int k0 = 0; k0 < 512; k0 += 8) {
      float v[8];
#pragma unroll
      for (int u2 = 0; u2 < 8; ++u2)
        v[u2] = h2f(E2[(size_t)(b*512 + k0 + u2) * MP + t]);
#pragma unroll
      for (int u2 = 0; u2 < 8; ++u2)
        S = fmaf(v[u2], sRr[k0 + u2], S);
    }
    __hip_atomic_fetch_add(&colsum[it * MP + t], S, __ATOMIC_RELAXED,
                           __HIP_MEMORY_SCOPE_AGENT);
    gbar(slots, it + 1, b, t);
    {
      float Sm = rd_f32(&colsum[it * MP + t]);
      sC[t] = 1.0f / (Sm + 1.0f);
    }
    __syncthreads();
  }
  rr_out[row] = sRr[t];
  if (b == 0) c_out[t] = sC[t];
}

// refined = 0.5*feats + 0.5 * W @ p2, W = E2 * R_i * C_j -- fp16 MFMA.
// A-frag: W computed per-element in F32 (R can exceed fp16 range; the full
// product W <= 1 by the Sinkhorn marginal bound), then cast to fp16.
__global__ __launch_bounds__(256) void k_refined2(const unsigned short* __restrict__ E2,
                                                  const float* __restrict__ rr,
                                                  const float* __restrict__ cc,
                                                  const _Float16* __restrict__ p2th,
                                                  const float* __restrict__ feats,
                                                  float* __restrict__ out) {
  __shared__ float scc[MP];
  const int t = threadIdx.x;
  scc[t] = cc[t];
  scc[t + 256] = cc[t + 256];
  __syncthreads();
  const int w = t >> 6, l = t & 63;
  const int m0 = blockIdx.x * 64 + w * 16;
  const int lr = l & 15, lk = l >> 4;
  const int rowA = m0 + lr;
  const float Rf = rr[rowA];
  h8 af[16];
  const us8* e8 = (const us8*)(E2 + (size_t)rowA * MP);
#pragma unroll
  for (int s = 0; s < 16; ++s) {
    us8 uv = e8[s * 4 + lk];
#pragma unroll
    for (int e = 0; e < 8; ++e) {
      float wv = h2f(uv[e]) * Rf * scc[s * 32 + lk * 8 + e];
      af[s][e] = (_Float16)wv;
    }
  }
  for (int ft = 0; ft < 8; ++ft) {
    f4 acc = {0.0f, 0.0f, 0.0f, 0.0f};
    const _Float16* bbase = p2th + (size_t)(ft * 16 + lr) * MP + lk * 8;
#pragma unroll
    for (int s = 0; s < 16; ++s) {
      h8 bf = *(const h8*)(bbase + s * 32);
      acc = __builtin_amdgcn_mfma_f32_16x16x32_f16(af[s], bf, acc, 0, 0, 0);
    }
#pragma unroll
    for (int r = 0; r < 4; ++r) {
      int row = m0 + lk * 4 + r;
      int col = ft * 16 + lr;
      out[(size_t)row * 128 + col] =
          0.5f * feats[(size_t)row * 128 + col] + 0.5f * acc[r];
    }
  }
}

// ---------------- launcher ----------------

extern "C" void kernel_launch(void* const* d_in, const int* in_sizes, int n_in,
                              void* d_out, int out_size, void* d_ws, size_t ws_size,
                              hipStream_t stream) {
  (void)in_sizes; (void)n_in; (void)out_size; (void)ws_size;
  const float* xyz   = (const float*)d_in[0];
  const float* feats = (const float*)d_in[1];
  float* out = (float*)d_out;
  char* ws = (char*)d_ws;

  auto al = [](size_t x) { return (x + 255) & ~(size_t)255; };
  // E-buffer (fp16, 64MB): holds E1 (sk1/pfeat), later overwritten by E2
  unsigned short* Ebuf = (unsigned short*)ws;
  size_t o = al((size_t)NP * MP * 2);
  float4* xyzs4 = (float4*)(ws + o); o += al((size_t)NP * 16);
  float* rbuf   = (float*)(ws + o);  o += al((size_t)NP * 4);
  float* ebnbuf = (float*)(ws + o);  o += al((size_t)NP * 4);
  float* cbuf   = (float*)(ws + o);  o += al((size_t)MP * 4);
  float* gcbuf  = (float*)(ws + o);  o += al((size_t)MP * 4);
  int*   cent   = (int*)(ws + o);    o += al((size_t)MP * 4);
  float4* pxyzs4 = (float4*)(ws + o); o += al((size_t)MP * 16);
  float* ge     = (float*)(ws + o);  o += al((size_t)MP * 4);
  float* meann  = (float*)(ws + o);  o += al((size_t)256);
  float* pf     = (float*)(ws + o);  o += al((size_t)MP * 128 * 4);
  float* p1     = (float*)(ws + o);  o += al((size_t)MP * 128 * 4);
  float* p2     = (float*)(ws + o);  o += al((size_t)MP * 128 * 4);
  _Float16* p2h = (_Float16*)(ws + o); o += al((size_t)MP * 128 * 2);
  _Float16* p2th = (_Float16*)(ws + o); o += al((size_t)MP * 128 * 2);
  float* colsumA = (float*)(ws + o); o += al((size_t)SKI * MP * 4);
  float* colsumB = (float*)(ws + o); o += al((size_t)SKI * MP * 4);
  unsigned long long* fslots = (unsigned long long*)(ws + o);
  o += al((size_t)3 * FNB * 8);
  int* bar1 = (int*)(ws + o); o += al((size_t)SKB2 * 4);
  int* bar2 = (int*)(ws + o); o += al((size_t)SKB2 * 4);
  float* partA = (float*)(ws + o); o += al((size_t)64 * MP * 128 * 4);
  _Float16* featsh = (_Float16*)partA;  // 16MB, reuses partA after pfeat_red

  hipMemsetAsync(colsumA, 0, (size_t)2 * SKI * MP * 4 + 256, stream);
  k_prep<<<dim3(256), dim3(256), 0, stream>>>(xyz, xyzs4, fslots, bar1, bar2);
  k_fps3<<<dim3(FNB), dim3(FPT), 0, stream>>>(xyzs4, cent, fslots);
  k_gather1<<<dim3(1), dim3(512), 0, stream>>>(xyz, cent, pxyzs4, meann);
  k_gatherf<<<dim3(512), dim3(128), 0, stream>>>(feats, cent, pf);
  k_ballpca<<<dim3(512), dim3(256), 0, stream>>>(xyzs4, pxyzs4, meann, ge);

  // sinkhorn 1 on precomputed E1 (factorized, exp-free, fence-free)
  k_e1<<<dim3(512), dim3(256), 0, stream>>>(xyzs4, pxyzs4, Ebuf);
  k_sk1<<<dim3(SKB2), dim3(512), 0, stream>>>(Ebuf, ge, rbuf, gcbuf, colsumA, bar1);

  k_pfeat_part<<<dim3(64, 8), dim3(128), 0, stream>>>(Ebuf, gcbuf, rbuf, feats, partA);
  k_pfeat_red<<<dim3(256), dim3(256), 0, stream>>>(partA, pf, p1);
  k_simtopk<<<dim3(512), dim3(128), 0, stream>>>(p1, p2, p2h, p2th);

  // feats -> fp16 (into dead partA region), fused MFMA sim + E2, sinkhorn 2
  k_feath<<<dim3(4096), dim3(256), 0, stream>>>(feats, featsh);
  k_simpt2<<<dim3(1024), dim3(256), 0, stream>>>(featsh, p2h, Ebuf, ebnbuf);
  k_sk2<<<dim3(SKB2), dim3(512), 0, stream>>>(Ebuf, ebnbuf, rbuf, cbuf, colsumB, bar2);
  k_refined2<<<dim3(1024), dim3(256), 0, stream>>>(Ebuf, rbuf, cbuf, p2th, feats, out);
}